// Round 14
// baseline (95.507 us; speedup 1.0000x reference)
//
#include <hip/hip_runtime.h>
#include <math.h>

#define CRF_B 2048
#define CRF_S 4096
#define LN2F  0.6931471805599453f

// Shared-exponent merge: A ∘= B, M = q[9] * 2^C. 27 FMA + single pow2 renorm.
#define CRF_MERGE(aq0,aq1,aq2,aq3,aq4,aq5,aq6,aq7,aq8,aC,asc,acn, \
                  bq0,bq1,bq2,bq3,bq4,bq5,bq6,bq7,bq8,bC,bsc,bcn) { \
    float r0_=aq0*bq0+aq1*bq3+aq2*bq6;                              \
    float r1_=aq0*bq1+aq1*bq4+aq2*bq7;                              \
    float r2_=aq0*bq2+aq1*bq5+aq2*bq8;                              \
    float r3_=aq3*bq0+aq4*bq3+aq5*bq6;                              \
    float r4_=aq3*bq1+aq4*bq4+aq5*bq7;                              \
    float r5_=aq3*bq2+aq4*bq5+aq5*bq8;                              \
    float r6_=aq6*bq0+aq7*bq3+aq8*bq6;                              \
    float r7_=aq6*bq1+aq7*bq4+aq8*bq7;                              \
    float r8_=aq6*bq2+aq7*bq5+aq8*bq8;                              \
    float mx_ = fmaxf(fmaxf(fmaxf(fmaxf(r0_,r1_),r2_),              \
                            fmaxf(fmaxf(r3_,r4_),r5_)),             \
                      fmaxf(fmaxf(r6_,r7_),r8_));                   \
    int ex_ = ((__float_as_int(mx_)>>23)&255)-127;                  \
    float sc_ = __int_as_float((127-ex_)<<23);                      \
    aq0=r0_*sc_; aq1=r1_*sc_; aq2=r2_*sc_;                          \
    aq3=r3_*sc_; aq4=r4_*sc_; aq5=r5_*sc_;                          \
    aq6=r6_*sc_; aq7=r7_*sc_; aq8=r8_*sc_;                          \
    aC = aC + bC + ex_;                                             \
    asc += bsc; acn += bcn; }

// One recursion step + emission-score select + transition-pair histogram.
#define CRF_STEP(tconst, E0, E1, E2) {                               \
    int tv_ = (int)((ttag >> (2*(tconst))) & 3u);                    \
    int mv_ = (int)((tmsk >> (tconst)) & 1u);                        \
    if (mv_ && !(((tconst) == 0) && (tid == 0))) {                   \
        float X0_ = __expf(E0), X1_ = __expf(E1), X2_ = __expf(E2);  \
        float n0_, n1_, n2_;                                         \
        n0_ = q0*Etr0 + q1*Etr3 + q2*Etr6;                           \
        n1_ = q0*Etr1 + q1*Etr4 + q2*Etr7;                           \
        n2_ = q0*Etr2 + q1*Etr5 + q2*Etr8;                           \
        q0 = n0_*X0_; q1 = n1_*X1_; q2 = n2_*X2_;                    \
        n0_ = q3*Etr0 + q4*Etr3 + q5*Etr6;                           \
        n1_ = q3*Etr1 + q4*Etr4 + q5*Etr7;                           \
        n2_ = q3*Etr2 + q4*Etr5 + q5*Etr8;                           \
        q3 = n0_*X0_; q4 = n1_*X1_; q5 = n2_*X2_;                    \
        n0_ = q6*Etr0 + q7*Etr3 + q8*Etr6;                           \
        n1_ = q6*Etr1 + q7*Etr4 + q8*Etr7;                           \
        n2_ = q6*Etr2 + q7*Etr5 + q8*Etr8;                           \
        q6 = n0_*X0_; q7 = n1_*X1_; q8 = n2_*X2_;                    \
        sem += (tv_ == 0) ? (E0) : ((tv_ == 1) ? (E1) : (E2));       \
        hist += 1ULL << (5 * (p * 3 + tv_));                         \
    }                                                                \
    p = tv_; }

#define CRF_RENORM() {                                               \
    float mx_ = fmaxf(fmaxf(fmaxf(fmaxf(q0,q1),q2),                  \
                            fmaxf(fmaxf(q3,q4),q5)),                 \
                      fmaxf(fmaxf(q6,q7),q8));                       \
    int ex_ = ((__float_as_int(mx_) >> 23) & 255) - 127;             \
    float sc_ = __int_as_float((127 - ex_) << 23);                   \
    q0 *= sc_; q1 *= sc_; q2 *= sc_;                                 \
    q3 *= sc_; q4 *= sc_; q5 *= sc_;                                 \
    q6 *= sc_; q7 *= sc_; q8 *= sc_;                                 \
    C += ex_; }

// ---------------------------------------------------------------------------
// Phase A: block = one row, 4 INDEPENDENT waves, ZERO LDS, ZERO barriers.
// Lane owns a 16-step chunk; trans via uniform s_loads; transition score via
// 5-bit x 9 histogram in a 64-bit reg (dotted with trans at the end); prev
// tag via shfl_up (+1 predicated load for lane 0). 6-level shfl merge; lane 0
// stores a 48-B wave partial. No head barrier, no tid0 tail.
// ---------------------------------------------------------------------------
__global__ __launch_bounds__(256, 6) void crf_chunkA(
    const float* __restrict__ em,     // B*S*3
    const float* __restrict__ trans,  // 9
    const int*   __restrict__ tags,   // B*S
    const int*   __restrict__ mask,   // B*S
    float* __restrict__ wsq)          // [B*4][12]
{
    const int tid = threadIdx.x;      // chunk id within row (0..255)
    const int w = tid >> 6, l = tid & 63;
    const int b = blockIdx.x;
    const long cbase = (long)b * CRF_S + (long)tid * 16;

    // ---- chunk loads (independent; compiler schedules) ----
    const float4* e4 = (const float4*)(em + cbase * 3);   // 192 B, aligned
    float4 ea0 = e4[0], ea1 = e4[1], ea2  = e4[2],  ea3  = e4[3];
    float4 ea4 = e4[4], ea5 = e4[5], ea6  = e4[6],  ea7  = e4[7];
    float4 ea8 = e4[8], ea9 = e4[9], ea10 = e4[10], ea11 = e4[11];
    const int4* t4 = (const int4*)(tags + cbase);
    const int4* m4 = (const int4*)(mask + cbase);
    int4 ta = t4[0], tb = t4[1], tc = t4[2], td = t4[3];
    int4 ma = m4[0], mb = m4[1], mc = m4[2], md = m4[3];
    int pload = 0;
    if (l == 0 && tid > 0) pload = tags[cbase - 1];       // 1 lane per wave

    // ---- uniform trans (s_loads) -> Etr ----
    float Etr0 = __expf(trans[0]), Etr1 = __expf(trans[1]), Etr2 = __expf(trans[2]);
    float Etr3 = __expf(trans[3]), Etr4 = __expf(trans[4]), Etr5 = __expf(trans[5]);
    float Etr6 = __expf(trans[6]), Etr7 = __expf(trans[7]), Etr8 = __expf(trans[8]);

    // ---- pack tags (2b) and mask (1b) into scalars ----
    unsigned ttag =  (unsigned)(ta.x & 3)        | ((unsigned)(ta.y & 3) << 2)
                  | ((unsigned)(ta.z & 3) << 4)  | ((unsigned)(ta.w & 3) << 6)
                  | ((unsigned)(tb.x & 3) << 8)  | ((unsigned)(tb.y & 3) << 10)
                  | ((unsigned)(tb.z & 3) << 12) | ((unsigned)(tb.w & 3) << 14)
                  | ((unsigned)(tc.x & 3) << 16) | ((unsigned)(tc.y & 3) << 18)
                  | ((unsigned)(tc.z & 3) << 20) | ((unsigned)(tc.w & 3) << 22)
                  | ((unsigned)(td.x & 3) << 24) | ((unsigned)(td.y & 3) << 26)
                  | ((unsigned)(td.z & 3) << 28) | ((unsigned)(td.w & 3) << 30);
    unsigned tmsk =  (unsigned)(ma.x != 0)        | ((unsigned)(ma.y != 0) << 1)
                  | ((unsigned)(ma.z != 0) << 2)  | ((unsigned)(ma.w != 0) << 3)
                  | ((unsigned)(mb.x != 0) << 4)  | ((unsigned)(mb.y != 0) << 5)
                  | ((unsigned)(mb.z != 0) << 6)  | ((unsigned)(mb.w != 0) << 7)
                  | ((unsigned)(mc.x != 0) << 8)  | ((unsigned)(mc.y != 0) << 9)
                  | ((unsigned)(mc.z != 0) << 10) | ((unsigned)(mc.w != 0) << 11)
                  | ((unsigned)(md.x != 0) << 12) | ((unsigned)(md.y != 0) << 13)
                  | ((unsigned)(md.z != 0) << 14) | ((unsigned)(md.w != 0) << 15);

    int lastTag = (int)((ttag >> 30) & 3u);
    int pup = __shfl_up(lastTag, 1);
    int p = (l == 0) ? (pload & 3) : pup;

    int cnt = __popc(tmsk & ((tid == 0) ? 0xFFFEu : 0xFFFFu));

    float q0=1.f,q1=0.f,q2=0.f, q3=0.f,q4=1.f,q5=0.f, q6=0.f,q7=0.f,q8=1.f;
    int C = 0;
    float sem = 0.f;
    unsigned long long hist = 0ULL;   // 9 x 5-bit transition-pair counts

    CRF_STEP( 0, ea0.x, ea0.y, ea0.z);
    CRF_STEP( 1, ea0.w, ea1.x, ea1.y);
    CRF_STEP( 2, ea1.z, ea1.w, ea2.x);
    CRF_STEP( 3, ea2.y, ea2.z, ea2.w);
    CRF_RENORM();
    CRF_STEP( 4, ea3.x, ea3.y, ea3.z);
    CRF_STEP( 5, ea3.w, ea4.x, ea4.y);
    CRF_STEP( 6, ea4.z, ea4.w, ea5.x);
    CRF_STEP( 7, ea5.y, ea5.z, ea5.w);
    CRF_RENORM();
    CRF_STEP( 8, ea6.x, ea6.y, ea6.z);
    CRF_STEP( 9, ea6.w, ea7.x, ea7.y);
    CRF_STEP(10, ea7.z, ea7.w, ea8.x);
    CRF_STEP(11, ea8.y, ea8.z, ea8.w);
    CRF_RENORM();
    CRF_STEP(12, ea9.x, ea9.y, ea9.z);
    CRF_STEP(13, ea9.w, ea10.x, ea10.y);
    CRF_STEP(14, ea10.z, ea10.w, ea11.x);
    CRF_STEP(15, ea11.y, ea11.z, ea11.w);
    CRF_RENORM();

    // transition score = hist . trans (uniform reloads, s_load)
    float str_sum = 0.f;
    #pragma unroll
    for (int i2 = 0; i2 < 9; ++i2)
        str_sum += (float)(int)((hist >> (5 * i2)) & 31ULL) * trans[i2];
    float score = str_sum + sem;

    // ---- per-wave shfl_down log-semiring reduction ----
    #pragma unroll
    for (int st = 1; st < 64; st <<= 1) {
        float nq0 = __shfl_down(q0, st), nq1 = __shfl_down(q1, st),
              nq2 = __shfl_down(q2, st), nq3 = __shfl_down(q3, st),
              nq4 = __shfl_down(q4, st), nq5 = __shfl_down(q5, st),
              nq6 = __shfl_down(q6, st), nq7 = __shfl_down(q7, st),
              nq8 = __shfl_down(q8, st);
        int   nC  = __shfl_down(C, st);
        float nsc = __shfl_down(score, st);
        int   ncn = __shfl_down(cnt, st);
        CRF_MERGE(q0,q1,q2,q3,q4,q5,q6,q7,q8,C,score,cnt,
                  nq0,nq1,nq2,nq3,nq4,nq5,nq6,nq7,nq8,nC,nsc,ncn);
    }

    if (l == 0) {
        float4* o = (float4*)(wsq + ((size_t)b * 4 + w) * 12);
        o[0] = make_float4(q0, q1, q2, q3);
        o[1] = make_float4(q4, q5, q6, q7);
        o[2] = make_float4(q8, score, __int_as_float(C), __int_as_float(cnt));
    }
}

// ---------------------------------------------------------------------------
// Phase B: ONE block x 1024 threads. Thread folds 4 wave partials for rows
// tid and tid+1024, applies the epilogue, accumulates (lp - score); block
// tree-reduce -> mean -> out[0].
// ---------------------------------------------------------------------------
__global__ __launch_bounds__(1024) void crf_combineB(
    const float* __restrict__ em,
    const float* __restrict__ startt,
    const float* __restrict__ endt,
    const int*   __restrict__ tags,
    const int*   __restrict__ mask,
    const float* __restrict__ wsq,
    float* __restrict__ out)
{
    __shared__ float sdata[1024];
    const int tid = threadIdx.x;
    float local = 0.f;

    #pragma unroll
    for (int rr = 0; rr < 2; ++rr) {
        const int row = tid + rr * 1024;
        const float4* pb = (const float4*)(wsq + (size_t)row * 4 * 12);
        float4 a0 = pb[0], a1 = pb[1], a2 = pb[2];
        float q0=a0.x,q1=a0.y,q2=a0.z,q3=a0.w,q4=a1.x,q5=a1.y,q6=a1.z,q7=a1.w,
              q8=a2.x;
        float score = a2.y;
        int C = __float_as_int(a2.z), cnt = __float_as_int(a2.w);
        #pragma unroll
        for (int w2 = 1; w2 < 4; ++w2) {
            float4 b0 = pb[3*w2+0], b1 = pb[3*w2+1], b2 = pb[3*w2+2];
            float m0=b0.x,m1=b0.y,m2=b0.z,m3=b0.w,m4=b1.x,m5=b1.y,m6=b1.z,
                  m7=b1.w,m8=b2.x;
            float msc = b2.y;
            int mC = __float_as_int(b2.z), mcn = __float_as_int(b2.w);
            CRF_MERGE(q0,q1,q2,q3,q4,q5,q6,q7,q8,C,score,cnt,
                      m0,m1,m2,m3,m4,m5,m6,m7,m8,mC,msc,mcn);
        }
        const long base = (long)row * CRF_S;
        float e0 = em[base*3+0], e1 = em[base*3+1], e2 = em[base*3+2];
        int tg0 = tags[base] & 3;
        int mk0 = (mask[base] != 0) ? 1 : 0;

        float la0 = startt[0] + e0;
        float la1 = startt[1] + e1;
        float la2 = startt[2] + e2;
        float am = fmaxf(fmaxf(la0, la1), la2);
        float w0  = __expf(la0 - am);
        float w1  = __expf(la1 - am);
        float w2v = __expf(la2 - am);
        float v0 = w0*q0 + w1*q3 + w2v*q6;
        float v1 = w0*q1 + w1*q4 + w2v*q7;
        float v2 = w0*q2 + w1*q5 + w2v*q8;
        float sum = v0 * __expf(endt[0]) + v1 * __expf(endt[1])
                  + v2 * __expf(endt[2]);
        float lp = am + (float)C * LN2F + __logf(sum);

        float sc = score + startt[tg0]
                 + ((tg0 == 0) ? e0 : (tg0 == 1) ? e1 : e2);
        int cn = cnt + mk0;
        int lastidx = (cn > 0) ? (cn - 1) : 0;
        sc += endt[tags[base + lastidx]];

        local += lp - sc;
    }

    sdata[tid] = local;
    __syncthreads();
    for (int off = 512; off > 0; off >>= 1) {
        if (tid < off) sdata[tid] += sdata[tid + off];
        __syncthreads();
    }
    if (tid == 0) out[0] = sdata[0] * (1.0f / (float)CRF_B);
}

extern "C" void kernel_launch(void* const* d_in, const int* in_sizes, int n_in,
                              void* d_out, int out_size, void* d_ws, size_t ws_size,
                              hipStream_t stream)
{
    const float* em     = (const float*)d_in[0];
    const float* trans  = (const float*)d_in[1];
    const float* startt = (const float*)d_in[2];
    const float* endt   = (const float*)d_in[3];
    const int*   tags   = (const int*)d_in[4];
    const int*   mask   = (const int*)d_in[5];
    float* out = (float*)d_out;

    float* wsq = (float*)d_ws;   // B*4*12 floats

    crf_chunkA<<<CRF_B, 256, 0, stream>>>(em, trans, tags, mask, wsq);
    crf_combineB<<<1, 1024, 0, stream>>>(em, startt, endt, tags, mask, wsq, out);
}

// Round 15
// 42.744 us; speedup vs baseline: 2.2344x; 2.2344x over previous
//
#include <hip/hip_runtime.h>
#include <math.h>

#define CRF_B 2048
#define CRF_S 4096
#define LN2F  0.6931471805599453f

// Shared-exponent merge: A ∘= B, M = q[9] * 2^C. 27 FMA + single pow2 renorm.
#define CRF_MERGE(aq0,aq1,aq2,aq3,aq4,aq5,aq6,aq7,aq8,aC,asc,acn, \
                  bq0,bq1,bq2,bq3,bq4,bq5,bq6,bq7,bq8,bC,bsc,bcn) { \
    float r0_=aq0*bq0+aq1*bq3+aq2*bq6;                              \
    float r1_=aq0*bq1+aq1*bq4+aq2*bq7;                              \
    float r2_=aq0*bq2+aq1*bq5+aq2*bq8;                              \
    float r3_=aq3*bq0+aq4*bq3+aq5*bq6;                              \
    float r4_=aq3*bq1+aq4*bq4+aq5*bq7;                              \
    float r5_=aq3*bq2+aq4*bq5+aq5*bq8;                              \
    float r6_=aq6*bq0+aq7*bq3+aq8*bq6;                              \
    float r7_=aq6*bq1+aq7*bq4+aq8*bq7;                              \
    float r8_=aq6*bq2+aq7*bq5+aq8*bq8;                              \
    float mx_ = fmaxf(fmaxf(fmaxf(fmaxf(r0_,r1_),r2_),              \
                            fmaxf(fmaxf(r3_,r4_),r5_)),             \
                      fmaxf(fmaxf(r6_,r7_),r8_));                   \
    int ex_ = ((__float_as_int(mx_)>>23)&255)-127;                  \
    float sc_ = __int_as_float((127-ex_)<<23);                      \
    aq0=r0_*sc_; aq1=r1_*sc_; aq2=r2_*sc_;                          \
    aq3=r3_*sc_; aq4=r4_*sc_; aq5=r5_*sc_;                          \
    aq6=r6_*sc_; aq7=r7_*sc_; aq8=r8_*sc_;                          \
    aC = aC + bC + ex_;                                             \
    asc += bsc; acn += bcn; }

// One recursion step: q (3x3, rows) <- (q · Etr) * diag(exp(e)).
#define CRF_STEP(tconst, E0, E1, E2) {                               \
    int tv_ = (int)((ttag >> (2*(tconst))) & 3u);                    \
    int mv_ = (int)((tmsk >> (tconst)) & 1u);                        \
    if (mv_ && !(((tconst) == 0) && (tid == 0))) {                   \
        float X0_ = __expf(E0), X1_ = __expf(E1), X2_ = __expf(E2);  \
        float n0_, n1_, n2_;                                         \
        n0_ = q0*Etr0 + q1*Etr3 + q2*Etr6;                           \
        n1_ = q0*Etr1 + q1*Etr4 + q2*Etr7;                           \
        n2_ = q0*Etr2 + q1*Etr5 + q2*Etr8;                           \
        q0 = n0_*X0_; q1 = n1_*X1_; q2 = n2_*X2_;                    \
        n0_ = q3*Etr0 + q4*Etr3 + q5*Etr6;                           \
        n1_ = q3*Etr1 + q4*Etr4 + q5*Etr7;                           \
        n2_ = q3*Etr2 + q4*Etr5 + q5*Etr8;                           \
        q3 = n0_*X0_; q4 = n1_*X1_; q5 = n2_*X2_;                    \
        n0_ = q6*Etr0 + q7*Etr3 + q8*Etr6;                           \
        n1_ = q6*Etr1 + q7*Etr4 + q8*Etr7;                           \
        n2_ = q6*Etr2 + q7*Etr5 + q8*Etr8;                           \
        q6 = n0_*X0_; q7 = n1_*X1_; q8 = n2_*X2_;                    \
        sem += (tv_ == 0) ? (E0) : ((tv_ == 1) ? (E1) : (E2));       \
    } }

#define CRF_RENORM() {                                               \
    float mx_ = fmaxf(fmaxf(fmaxf(fmaxf(q0,q1),q2),                  \
                            fmaxf(fmaxf(q3,q4),q5)),                 \
                      fmaxf(fmaxf(q6,q7),q8));                       \
    int ex_ = ((__float_as_int(mx_) >> 23) & 255) - 127;             \
    float sc_ = __int_as_float((127 - ex_) << 23);                   \
    q0 *= sc_; q1 *= sc_; q2 *= sc_;                                 \
    q3 *= sc_; q4 *= sc_; q5 *= sc_;                                 \
    q6 *= sc_; q7 *= sc_; q8 *= sc_;                                 \
    C += ex_; }

// ---------------------------------------------------------------------------
// One block = one batch row. 4 waves; wave stages its own 1024-step em
// window into LDS with 12 perfectly COALESCED float4 loads (8 line-touches
// per instruction instead of 64 -> kills the TA/L1 transaction bottleneck),
// barrier-free (same-wave ds write->read). Each lane bulk-reads its 192-B
// chunk (12 x ds_read_b128, chunk stride 52 dwords) and runs the proven
// register-resident 16-step recursion. Tags/mask stay direct per-lane int4.
// ---------------------------------------------------------------------------
__global__ __launch_bounds__(256, 4) void crf_row_kernel(
    const float* __restrict__ em,     // B*S*3
    const float* __restrict__ trans,  // 9
    const float* __restrict__ startt, // 3
    const float* __restrict__ endt,   // 3
    const int*   __restrict__ tags,   // B*S
    const int*   __restrict__ mask,   // B*S
    float* __restrict__ perb)         // B
{
    __shared__ float s_em[4][64 * 52];   // 53,248 B; wave-private windows
    __shared__ float s_tr[9];
    __shared__ float s_rq[4][10];
    __shared__ int   s_rc[4][2];

    const int tid = threadIdx.x;      // chunk id within row (0..255)
    const int w = tid >> 6, l = tid & 63;
    const int b = blockIdx.x;
    const long cbase = (long)b * CRF_S + (long)tid * 16;

    if (tid < 9) s_tr[tid] = trans[tid];

    // ---- tags/mask: direct per-lane loads (modest TA cost) ----
    const int4* t4 = (const int4*)(tags + cbase);
    const int4* m4 = (const int4*)(mask + cbase);
    int4 ta = t4[0], tb = t4[1], tc = t4[2], td = t4[3];
    int4 ma = m4[0], mb = m4[1], mc = m4[2], md = m4[3];
    int p = 0;
    if (tid > 0) p = tags[cbase - 1] & 3;

    // ---- COALESCED em staging: wave's 1024-step window, 12 float4/lane ----
    const float4* gsrc = (const float4*)(em + ((long)b * CRF_S + (long)w * 1024) * 3);
    float* wbase = &s_em[w][0];
    #pragma unroll
    for (int k = 0; k < 12; ++k) {
        float4 v = gsrc[k * 64 + l];
        int g = k * 64 + l;                 // window float4 index (0..767)
        int c = (g * 683) >> 13;            // g / 12 (exact for g < 768)
        int r = g - c * 12;
        *(float4*)(wbase + c * 52 + r * 4) = v;   // chunk stride 52 dw (16B-al)
    }
    __syncthreads();   // s_tr visibility (em staging is wave-private)

    // ---- bulk LDS -> registers: lane's chunk, 12 x ds_read_b128 ----
    const float4* ce = (const float4*)(wbase + l * 52);
    float4 ea0 = ce[0], ea1 = ce[1], ea2  = ce[2],  ea3  = ce[3];
    float4 ea4 = ce[4], ea5 = ce[5], ea6  = ce[6],  ea7  = ce[7];
    float4 ea8 = ce[8], ea9 = ce[9], ea10 = ce[10], ea11 = ce[11];

    // ---- pack tags (2b) and mask (1b) into scalars ----
    unsigned ttag =  (unsigned)(ta.x & 3)        | ((unsigned)(ta.y & 3) << 2)
                  | ((unsigned)(ta.z & 3) << 4)  | ((unsigned)(ta.w & 3) << 6)
                  | ((unsigned)(tb.x & 3) << 8)  | ((unsigned)(tb.y & 3) << 10)
                  | ((unsigned)(tb.z & 3) << 12) | ((unsigned)(tb.w & 3) << 14)
                  | ((unsigned)(tc.x & 3) << 16) | ((unsigned)(tc.y & 3) << 18)
                  | ((unsigned)(tc.z & 3) << 20) | ((unsigned)(tc.w & 3) << 22)
                  | ((unsigned)(td.x & 3) << 24) | ((unsigned)(td.y & 3) << 26)
                  | ((unsigned)(td.z & 3) << 28) | ((unsigned)(td.w & 3) << 30);
    unsigned tmsk =  (unsigned)(ma.x != 0)        | ((unsigned)(ma.y != 0) << 1)
                  | ((unsigned)(ma.z != 0) << 2)  | ((unsigned)(ma.w != 0) << 3)
                  | ((unsigned)(mb.x != 0) << 4)  | ((unsigned)(mb.y != 0) << 5)
                  | ((unsigned)(mb.z != 0) << 6)  | ((unsigned)(mb.w != 0) << 7)
                  | ((unsigned)(mc.x != 0) << 8)  | ((unsigned)(mc.y != 0) << 9)
                  | ((unsigned)(mc.z != 0) << 10) | ((unsigned)(mc.w != 0) << 11)
                  | ((unsigned)(md.x != 0) << 12) | ((unsigned)(md.y != 0) << 13)
                  | ((unsigned)(md.z != 0) << 14) | ((unsigned)(md.w != 0) << 15);

    // ---- transition-score pre-pass: 16 independent LDS lookups ----
    float str_sum = 0.f;
    {
        int pr = p;
        #pragma unroll
        for (int t = 0; t < 16; ++t) {
            int tv = (int)((ttag >> (2 * t)) & 3u);
            if (((tmsk >> t) & 1u) && !((t == 0) && (tid == 0)))
                str_sum += s_tr[pr * 3 + tv];
            pr = tv;
        }
    }
    int cnt = __popc(tmsk & ((tid == 0) ? 0xFFFEu : 0xFFFFu));

    float Etr0 = __expf(s_tr[0]), Etr1 = __expf(s_tr[1]), Etr2 = __expf(s_tr[2]);
    float Etr3 = __expf(s_tr[3]), Etr4 = __expf(s_tr[4]), Etr5 = __expf(s_tr[5]);
    float Etr6 = __expf(s_tr[6]), Etr7 = __expf(s_tr[7]), Etr8 = __expf(s_tr[8]);

    float q0=1.f,q1=0.f,q2=0.f, q3=0.f,q4=1.f,q5=0.f, q6=0.f,q7=0.f,q8=1.f;
    int C = 0;
    float sem = 0.f;   // emission part of gold score

    float et0 = ea0.x, et1 = ea0.y, et2 = ea0.z;   // em[b,chunk,0,:] (epilogue)

    CRF_STEP( 0, ea0.x, ea0.y, ea0.z);
    CRF_STEP( 1, ea0.w, ea1.x, ea1.y);
    CRF_STEP( 2, ea1.z, ea1.w, ea2.x);
    CRF_STEP( 3, ea2.y, ea2.z, ea2.w);
    CRF_RENORM();
    CRF_STEP( 4, ea3.x, ea3.y, ea3.z);
    CRF_STEP( 5, ea3.w, ea4.x, ea4.y);
    CRF_STEP( 6, ea4.z, ea4.w, ea5.x);
    CRF_STEP( 7, ea5.y, ea5.z, ea5.w);
    CRF_RENORM();
    CRF_STEP( 8, ea6.x, ea6.y, ea6.z);
    CRF_STEP( 9, ea6.w, ea7.x, ea7.y);
    CRF_STEP(10, ea7.z, ea7.w, ea8.x);
    CRF_STEP(11, ea8.y, ea8.z, ea8.w);
    CRF_RENORM();
    CRF_STEP(12, ea9.x, ea9.y, ea9.z);
    CRF_STEP(13, ea9.w, ea10.x, ea10.y);
    CRF_STEP(14, ea10.z, ea10.w, ea11.x);
    CRF_STEP(15, ea11.y, ea11.z, ea11.w);
    CRF_RENORM();

    float score = str_sum + sem;

    // ---- per-wave shfl_down log-semiring reduction ----
    #pragma unroll
    for (int st = 1; st < 64; st <<= 1) {
        float nq0 = __shfl_down(q0, st), nq1 = __shfl_down(q1, st),
              nq2 = __shfl_down(q2, st), nq3 = __shfl_down(q3, st),
              nq4 = __shfl_down(q4, st), nq5 = __shfl_down(q5, st),
              nq6 = __shfl_down(q6, st), nq7 = __shfl_down(q7, st),
              nq8 = __shfl_down(q8, st);
        int   nC  = __shfl_down(C, st);
        float nsc = __shfl_down(score, st);
        int   ncn = __shfl_down(cnt, st);
        CRF_MERGE(q0,q1,q2,q3,q4,q5,q6,q7,q8,C,score,cnt,
                  nq0,nq1,nq2,nq3,nq4,nq5,nq6,nq7,nq8,nC,nsc,ncn);
    }

    if (l == 0) {
        s_rq[w][0]=q0; s_rq[w][1]=q1; s_rq[w][2]=q2;
        s_rq[w][3]=q3; s_rq[w][4]=q4; s_rq[w][5]=q5;
        s_rq[w][6]=q6; s_rq[w][7]=q7; s_rq[w][8]=q8;
        s_rq[w][9]=score;
        s_rc[w][0]=C;  s_rc[w][1]=cnt;
    }
    __syncthreads();

    if (tid == 0) {
        float a0=q0, a1=q1, a2=q2, a3=q3, a4=q4, a5=q5, a6=q6, a7=q7, a8=q8;
        float asc = score;
        int AC = C, acn = cnt;
        #pragma unroll
        for (int w2 = 1; w2 < 4; ++w2) {
            float m0=s_rq[w2][0], m1=s_rq[w2][1], m2=s_rq[w2][2],
                  m3=s_rq[w2][3], m4=s_rq[w2][4], m5=s_rq[w2][5],
                  m6=s_rq[w2][6], m7=s_rq[w2][7], m8=s_rq[w2][8];
            float msc = s_rq[w2][9];
            int mC = s_rc[w2][0], mcn = s_rc[w2][1];
            CRF_MERGE(a0,a1,a2,a3,a4,a5,a6,a7,a8,AC,asc,acn,
                      m0,m1,m2,m3,m4,m5,m6,m7,m8,mC,msc,mcn);
        }
        // ---- epilogue (tid 0 holds et0..2 = em[b,0,:], tag0, mask0) ----
        int tg0 = (int)(ttag & 3u), mk0 = (int)(tmsk & 1u);
        float la0 = startt[0] + et0;
        float la1 = startt[1] + et1;
        float la2 = startt[2] + et2;
        float am = fmaxf(fmaxf(la0, la1), la2);
        float w0  = __expf(la0 - am);
        float w1  = __expf(la1 - am);
        float w2v = __expf(la2 - am);
        float v0 = w0*a0 + w1*a3 + w2v*a6;
        float v1 = w0*a1 + w1*a4 + w2v*a7;
        float v2 = w0*a2 + w1*a5 + w2v*a8;
        float sum = v0 * __expf(endt[0]) + v1 * __expf(endt[1])
                  + v2 * __expf(endt[2]);
        float lp = am + (float)AC * LN2F + __logf(sum);

        float sc = asc + startt[tg0]
                 + ((tg0 == 0) ? et0 : (tg0 == 1) ? et1 : et2);
        int cn = acn + mk0;
        int lastidx = (cn > 0) ? (cn - 1) : 0;
        sc += endt[tags[(long)b * CRF_S + lastidx]];

        perb[b] = lp - sc;
    }
}

// ---------------------------------------------------------------------------
// Deterministic mean over B values.
// ---------------------------------------------------------------------------
__global__ __launch_bounds__(256) void crf_reduce_kernel(
    const float* __restrict__ perb, float* __restrict__ out)
{
    __shared__ float sdata[256];
    const int tid = threadIdx.x;
    float s = 0.f;
    for (int i = tid; i < CRF_B; i += 256) s += perb[i];
    sdata[tid] = s;
    __syncthreads();
    for (int off = 128; off > 0; off >>= 1) {
        if (tid < off) sdata[tid] += sdata[tid + off];
        __syncthreads();
    }
    if (tid == 0) out[0] = sdata[0] * (1.0f / (float)CRF_B);
}

extern "C" void kernel_launch(void* const* d_in, const int* in_sizes, int n_in,
                              void* d_out, int out_size, void* d_ws, size_t ws_size,
                              hipStream_t stream)
{
    const float* em     = (const float*)d_in[0];
    const float* trans  = (const float*)d_in[1];
    const float* startt = (const float*)d_in[2];
    const float* endt   = (const float*)d_in[3];
    const int*   tags   = (const int*)d_in[4];
    const int*   mask   = (const int*)d_in[5];
    float* out = (float*)d_out;

    float* perb = (float*)d_ws;   // B floats

    crf_row_kernel<<<CRF_B, 256, 0, stream>>>(
        em, trans, startt, endt, tags, mask, perb);
    crf_reduce_kernel<<<1, 256, 0, stream>>>(perb, out);
}

// Round 16
// 41.954 us; speedup vs baseline: 2.2765x; 1.0188x over previous
//
#include <hip/hip_runtime.h>
#include <hip/hip_fp16.h>
#include <math.h>

#define CRF_B 2048
#define CRF_S 4096
#define LN2F  0.6931471805599453f

#define ULO(u) __low2float(*(const __half2*)&(u))
#define UHI(u) __high2float(*(const __half2*)&(u))

// Shared-exponent merge: A ∘= B, M = q[9] * 2^C. 27 FMA + single pow2 renorm.
#define CRF_MERGE(aq0,aq1,aq2,aq3,aq4,aq5,aq6,aq7,aq8,aC,asc,acn, \
                  bq0,bq1,bq2,bq3,bq4,bq5,bq6,bq7,bq8,bC,bsc,bcn) { \
    float r0_=aq0*bq0+aq1*bq3+aq2*bq6;                              \
    float r1_=aq0*bq1+aq1*bq4+aq2*bq7;                              \
    float r2_=aq0*bq2+aq1*bq5+aq2*bq8;                              \
    float r3_=aq3*bq0+aq4*bq3+aq5*bq6;                              \
    float r4_=aq3*bq1+aq4*bq4+aq5*bq7;                              \
    float r5_=aq3*bq2+aq4*bq5+aq5*bq8;                              \
    float r6_=aq6*bq0+aq7*bq3+aq8*bq6;                              \
    float r7_=aq6*bq1+aq7*bq4+aq8*bq7;                              \
    float r8_=aq6*bq2+aq7*bq5+aq8*bq8;                              \
    float mx_ = fmaxf(fmaxf(fmaxf(fmaxf(r0_,r1_),r2_),              \
                            fmaxf(fmaxf(r3_,r4_),r5_)),             \
                      fmaxf(fmaxf(r6_,r7_),r8_));                   \
    int ex_ = ((__float_as_int(mx_)>>23)&255)-127;                  \
    float sc_ = __int_as_float((127-ex_)<<23);                      \
    aq0=r0_*sc_; aq1=r1_*sc_; aq2=r2_*sc_;                          \
    aq3=r3_*sc_; aq4=r4_*sc_; aq5=r5_*sc_;                          \
    aq6=r6_*sc_; aq7=r7_*sc_; aq8=r8_*sc_;                          \
    aC = aC + bC + ex_;                                             \
    asc += bsc; acn += bcn; }

// One recursion step: q (3x3, rows) <- (q · Etr) * diag(exp(e)).
#define CRF_STEP(tconst, E0, E1, E2) {                               \
    int tv_ = (int)((ttag >> (2*(tconst))) & 3u);                    \
    int mv_ = (int)((tmsk >> (tconst)) & 1u);                        \
    if (mv_ && !(((tconst) == 0) && (tid == 0))) {                   \
        float e0_ = (E0), e1_ = (E1), e2_ = (E2);                    \
        float X0_ = __expf(e0_), X1_ = __expf(e1_), X2_ = __expf(e2_); \
        float n0_, n1_, n2_;                                         \
        n0_ = q0*Etr0 + q1*Etr3 + q2*Etr6;                           \
        n1_ = q0*Etr1 + q1*Etr4 + q2*Etr7;                           \
        n2_ = q0*Etr2 + q1*Etr5 + q2*Etr8;                           \
        q0 = n0_*X0_; q1 = n1_*X1_; q2 = n2_*X2_;                    \
        n0_ = q3*Etr0 + q4*Etr3 + q5*Etr6;                           \
        n1_ = q3*Etr1 + q4*Etr4 + q5*Etr7;                           \
        n2_ = q3*Etr2 + q4*Etr5 + q5*Etr8;                           \
        q3 = n0_*X0_; q4 = n1_*X1_; q5 = n2_*X2_;                    \
        n0_ = q6*Etr0 + q7*Etr3 + q8*Etr6;                           \
        n1_ = q6*Etr1 + q7*Etr4 + q8*Etr7;                           \
        n2_ = q6*Etr2 + q7*Etr5 + q8*Etr8;                           \
        q6 = n0_*X0_; q7 = n1_*X1_; q8 = n2_*X2_;                    \
        sem += (tv_ == 0) ? e0_ : ((tv_ == 1) ? e1_ : e2_);          \
    } }

#define CRF_RENORM() {                                               \
    float mx_ = fmaxf(fmaxf(fmaxf(fmaxf(q0,q1),q2),                  \
                            fmaxf(fmaxf(q3,q4),q5)),                 \
                      fmaxf(fmaxf(q6,q7),q8));                       \
    int ex_ = ((__float_as_int(mx_) >> 23) & 255) - 127;             \
    float sc_ = __int_as_float((127 - ex_) << 23);                   \
    q0 *= sc_; q1 *= sc_; q2 *= sc_;                                 \
    q3 *= sc_; q4 *= sc_; q5 *= sc_;                                 \
    q6 *= sc_; q7 *= sc_; q8 *= sc_;                                 \
    C += ex_; }

// ---------------------------------------------------------------------------
// One block = one row, 4 waves. Wave stages its 1024-step window:
//   em  -> fp16 LDS (12 coalesced float4 loads, chunk stride 56 halves=112B,
//          16B-aligned so chunk reads are 6 x ds_read_b128)
//   t/m -> u16-per-4-steps LDS (8 coalesced int4 loads, packed)
// Line-touches/wave: ~160 (vs ~1030 uncoalesced). LDS ~31KB -> 5 blocks/CU.
// Then the proven register-resident 16-step recursion + shfl merge.
// ---------------------------------------------------------------------------
__global__ __launch_bounds__(256, 5) void crf_row_kernel(
    const float* __restrict__ em,     // B*S*3
    const float* __restrict__ trans,  // 9
    const float* __restrict__ startt, // 3
    const float* __restrict__ endt,   // 3
    const int*   __restrict__ tags,   // B*S
    const int*   __restrict__ mask,   // B*S
    float* __restrict__ perb)         // B
{
    __shared__ __half         s_em[4][64 * 56];   // 28,672 B
    __shared__ unsigned short s_tm[4][256];       //  2,048 B
    __shared__ float s_tr[9];
    __shared__ float s_rq[4][10];
    __shared__ int   s_rc[4][2];

    const int tid = threadIdx.x;      // chunk id within row (0..255)
    const int w = tid >> 6, l = tid & 63;
    const int b = blockIdx.x;
    const long cbase = (long)b * CRF_S + (long)tid * 16;
    const long wbase = (long)b * CRF_S + (long)w * 1024;

    if (tid < 9) s_tr[tid] = trans[tid];

    // ---- coalesced em staging -> fp16 LDS ----
    const float4* gsrc = (const float4*)(em + wbase * 3);
    __half* emw = &s_em[w][0];
    #pragma unroll
    for (int k = 0; k < 12; ++k) {
        int g = k * 64 + l;                 // window float4 index (0..767)
        float4 v = gsrc[g];
        int c = (g * 683) >> 13;            // g / 12 exact for g < 768
        int r = (g - c * 12) * 4;           // half offset in chunk (0..44)
        __half2 ha = __floats2half2_rn(v.x, v.y);
        __half2 hb = __floats2half2_rn(v.z, v.w);
        uint2 pk;
        pk.x = *(unsigned*)&ha; pk.y = *(unsigned*)&hb;
        *(uint2*)(emw + c * 56 + r) = pk;   // byte 112c+2r, 8B-aligned
    }
    // ---- coalesced tags/mask staging -> u16 per 4-step group ----
    const int4* t4 = (const int4*)(tags + wbase);
    const int4* m4 = (const int4*)(mask + wbase);
    #pragma unroll
    for (int k = 0; k < 4; ++k) {
        int g = k * 64 + l;                 // group index (0..255)
        int4 tg = t4[g];
        int4 mk = m4[g];
        unsigned u = (unsigned)(tg.x & 3)        | ((unsigned)(tg.y & 3) << 2)
                   | ((unsigned)(tg.z & 3) << 4) | ((unsigned)(tg.w & 3) << 6)
                   | ((unsigned)(mk.x != 0) << 8) | ((unsigned)(mk.y != 0) << 9)
                   | ((unsigned)(mk.z != 0) << 10)| ((unsigned)(mk.w != 0) << 11);
        s_tm[w][g] = (unsigned short)u;
    }
    int p = 0;
    if (tid > 0) p = tags[cbase - 1] & 3;

    __syncthreads();

    // ---- chunk reads: 6 x b128 (em halves) + 1 x b64 (tm) ----
    const char* cbytes = (const char*)(emw) + 112 * l;
    uint4 ua = *(const uint4*)(cbytes +  0);
    uint4 ub = *(const uint4*)(cbytes + 16);
    uint4 uc = *(const uint4*)(cbytes + 32);
    uint4 ud = *(const uint4*)(cbytes + 48);
    uint4 ue = *(const uint4*)(cbytes + 64);
    uint4 uf = *(const uint4*)(cbytes + 80);
    ushort4 tmv = *(const ushort4*)&s_tm[w][4 * l];

    unsigned ttag =  (unsigned)(tmv.x & 0xff)
                  | ((unsigned)(tmv.y & 0xff) << 8)
                  | ((unsigned)(tmv.z & 0xff) << 16)
                  | ((unsigned)(tmv.w & 0xff) << 24);
    unsigned tmsk =  (unsigned)((tmv.x >> 8) & 0xf)
                  | ((unsigned)((tmv.y >> 8) & 0xf) << 4)
                  | ((unsigned)((tmv.z >> 8) & 0xf) << 8)
                  | ((unsigned)((tmv.w >> 8) & 0xf) << 12);

    // ---- transition-score pre-pass: independent LDS lookups ----
    float str_sum = 0.f;
    {
        int pr = p;
        #pragma unroll
        for (int t = 0; t < 16; ++t) {
            int tv = (int)((ttag >> (2 * t)) & 3u);
            if (((tmsk >> t) & 1u) && !((t == 0) && (tid == 0)))
                str_sum += s_tr[pr * 3 + tv];
            pr = tv;
        }
    }
    int cnt = __popc(tmsk & ((tid == 0) ? 0xFFFEu : 0xFFFFu));

    float Etr0 = __expf(s_tr[0]), Etr1 = __expf(s_tr[1]), Etr2 = __expf(s_tr[2]);
    float Etr3 = __expf(s_tr[3]), Etr4 = __expf(s_tr[4]), Etr5 = __expf(s_tr[5]);
    float Etr6 = __expf(s_tr[6]), Etr7 = __expf(s_tr[7]), Etr8 = __expf(s_tr[8]);

    float q0=1.f,q1=0.f,q2=0.f, q3=0.f,q4=1.f,q5=0.f, q6=0.f,q7=0.f,q8=1.f;
    int C = 0;
    float sem = 0.f;

    float et0 = ULO(ua.x), et1 = UHI(ua.x), et2 = ULO(ua.y);  // step-0 em

    CRF_STEP( 0, ULO(ua.x), UHI(ua.x), ULO(ua.y));
    CRF_STEP( 1, UHI(ua.y), ULO(ua.z), UHI(ua.z));
    CRF_STEP( 2, ULO(ua.w), UHI(ua.w), ULO(ub.x));
    CRF_STEP( 3, UHI(ub.x), ULO(ub.y), UHI(ub.y));
    CRF_RENORM();
    CRF_STEP( 4, ULO(ub.z), UHI(ub.z), ULO(ub.w));
    CRF_STEP( 5, UHI(ub.w), ULO(uc.x), UHI(uc.x));
    CRF_STEP( 6, ULO(uc.y), UHI(uc.y), ULO(uc.z));
    CRF_STEP( 7, UHI(uc.z), ULO(uc.w), UHI(uc.w));
    CRF_RENORM();
    CRF_STEP( 8, ULO(ud.x), UHI(ud.x), ULO(ud.y));
    CRF_STEP( 9, UHI(ud.y), ULO(ud.z), UHI(ud.z));
    CRF_STEP(10, ULO(ud.w), UHI(ud.w), ULO(ue.x));
    CRF_STEP(11, UHI(ue.x), ULO(ue.y), UHI(ue.y));
    CRF_RENORM();
    CRF_STEP(12, ULO(ue.z), UHI(ue.z), ULO(ue.w));
    CRF_STEP(13, UHI(ue.w), ULO(uf.x), UHI(uf.x));
    CRF_STEP(14, ULO(uf.y), UHI(uf.y), ULO(uf.z));
    CRF_STEP(15, UHI(uf.z), ULO(uf.w), UHI(uf.w));
    CRF_RENORM();

    float score = str_sum + sem;

    // ---- per-wave shfl_down log-semiring reduction ----
    #pragma unroll
    for (int st = 1; st < 64; st <<= 1) {
        float nq0 = __shfl_down(q0, st), nq1 = __shfl_down(q1, st),
              nq2 = __shfl_down(q2, st), nq3 = __shfl_down(q3, st),
              nq4 = __shfl_down(q4, st), nq5 = __shfl_down(q5, st),
              nq6 = __shfl_down(q6, st), nq7 = __shfl_down(q7, st),
              nq8 = __shfl_down(q8, st);
        int   nC  = __shfl_down(C, st);
        float nsc = __shfl_down(score, st);
        int   ncn = __shfl_down(cnt, st);
        CRF_MERGE(q0,q1,q2,q3,q4,q5,q6,q7,q8,C,score,cnt,
                  nq0,nq1,nq2,nq3,nq4,nq5,nq6,nq7,nq8,nC,nsc,ncn);
    }

    if (l == 0) {
        s_rq[w][0]=q0; s_rq[w][1]=q1; s_rq[w][2]=q2;
        s_rq[w][3]=q3; s_rq[w][4]=q4; s_rq[w][5]=q5;
        s_rq[w][6]=q6; s_rq[w][7]=q7; s_rq[w][8]=q8;
        s_rq[w][9]=score;
        s_rc[w][0]=C;  s_rc[w][1]=cnt;
    }
    __syncthreads();

    if (tid == 0) {
        float a0=q0, a1=q1, a2=q2, a3=q3, a4=q4, a5=q5, a6=q6, a7=q7, a8=q8;
        float asc = score;
        int AC = C, acn = cnt;
        #pragma unroll
        for (int w2 = 1; w2 < 4; ++w2) {
            float m0=s_rq[w2][0], m1=s_rq[w2][1], m2=s_rq[w2][2],
                  m3=s_rq[w2][3], m4=s_rq[w2][4], m5=s_rq[w2][5],
                  m6=s_rq[w2][6], m7=s_rq[w2][7], m8=s_rq[w2][8];
            float msc = s_rq[w2][9];
            int mC = s_rc[w2][0], mcn = s_rc[w2][1];
            CRF_MERGE(a0,a1,a2,a3,a4,a5,a6,a7,a8,AC,asc,acn,
                      m0,m1,m2,m3,m4,m5,m6,m7,m8,mC,msc,mcn);
        }
        int tg0 = (int)(ttag & 3u), mk0 = (int)(tmsk & 1u);
        float la0 = startt[0] + et0;
        float la1 = startt[1] + et1;
        float la2 = startt[2] + et2;
        float am = fmaxf(fmaxf(la0, la1), la2);
        float w0  = __expf(la0 - am);
        float w1  = __expf(la1 - am);
        float w2v = __expf(la2 - am);
        float v0 = w0*a0 + w1*a3 + w2v*a6;
        float v1 = w0*a1 + w1*a4 + w2v*a7;
        float v2 = w0*a2 + w1*a5 + w2v*a8;
        float sum = v0 * __expf(endt[0]) + v1 * __expf(endt[1])
                  + v2 * __expf(endt[2]);
        float lp = am + (float)AC * LN2F + __logf(sum);

        float sc = asc + startt[tg0]
                 + ((tg0 == 0) ? et0 : (tg0 == 1) ? et1 : et2);
        int cn = acn + mk0;
        int lastidx = (cn > 0) ? (cn - 1) : 0;
        sc += endt[tags[(long)b * CRF_S + lastidx]];

        perb[b] = lp - sc;
    }
}

// ---------------------------------------------------------------------------
// Deterministic mean over B values.
// ---------------------------------------------------------------------------
__global__ __launch_bounds__(256) void crf_reduce_kernel(
    const float* __restrict__ perb, float* __restrict__ out)
{
    __shared__ float sdata[256];
    const int tid = threadIdx.x;
    float s = 0.f;
    for (int i = tid; i < CRF_B; i += 256) s += perb[i];
    sdata[tid] = s;
    __syncthreads();
    for (int off = 128; off > 0; off >>= 1) {
        if (tid < off) sdata[tid] += sdata[tid + off];
        __syncthreads();
    }
    if (tid == 0) out[0] = sdata[0] * (1.0f / (float)CRF_B);
}

extern "C" void kernel_launch(void* const* d_in, const int* in_sizes, int n_in,
                              void* d_out, int out_size, void* d_ws, size_t ws_size,
                              hipStream_t stream)
{
    const float* em     = (const float*)d_in[0];
    const float* trans  = (const float*)d_in[1];
    const float* startt = (const float*)d_in[2];
    const float* endt   = (const float*)d_in[3];
    const int*   tags   = (const int*)d_in[4];
    const int*   mask   = (const int*)d_in[5];
    float* out = (float*)d_out;

    float* perb = (float*)d_ws;   // B floats

    crf_row_kernel<<<CRF_B, 256, 0, stream>>>(
        em, trans, startt, endt, tags, mask, perb);
    crf_reduce_kernel<<<1, 256, 0, stream>>>(perb, out);
}